// Round 3
// baseline (670.408 us; speedup 1.0000x reference)
//
#include <hip/hip_runtime.h>
#include <hip/hip_bf16.h>

// TalkingHeads: BS=2, C_IN=512, SEQ=1024, DK=DV=64, H=16.
// *** Inputs and output are FLOAT32 (per reference setup_inputs) ***
// Compute in bf16 MFMA; fp32 accumulate; intermediates (Q/K/V, O) bf16 in ws.
// K2 does Wl/Ww head mixes + softmax in VALU fp32 (clamped, no NaN possible).

#define B_S  2
#define C_INN 512
#define SEQL 1024
#define D_K  64
#define N_H  16

typedef __attribute__((ext_vector_type(4))) float floatx4;
typedef __attribute__((ext_vector_type(8))) short short8;

static __device__ __forceinline__ unsigned short f2bf(float f) {
  union { float f; unsigned int i; } x; x.f = f;
  return (unsigned short)((x.i + 0x7fffu + ((x.i >> 16) & 1u)) >> 16);
}

// ---------------------------------------------------------------------------
// Kernel 1: QKV projection (fp32 in, bf16 out).
// Q,K -> [b][h][s][d] bf16 ; V -> [b][v][d][s] bf16.
// GEMM per (b,p): M=s(1024), N=(d*16+h)(1024), K=c(512). grid(16,16, b*3+p).
// ---------------------------------------------------------------------------
__global__ __launch_bounds__(256) void ath_qkv(
    const float* __restrict__ inp,
    const float* __restrict__ Wq,
    const float* __restrict__ Wk,
    const float* __restrict__ Wv,
    const float* __restrict__ Aq,
    const float* __restrict__ Ak,
    const float* __restrict__ Av,
    unsigned short* __restrict__ ws)
{
  const int sblk = blockIdx.x;
  const int nblk = blockIdx.y;
  const int z = blockIdx.z;
  const int b = z / 3, p = z % 3;
  const float* W  = (p == 0) ? Wq : ((p == 1) ? Wk : Wv);
  const float* Ap = (p == 0) ? Aq : ((p == 1) ? Ak : Av);
  const float sig = 1.0f / (1.0f + __expf(-Ap[0]));

  __shared__ __align__(16) unsigned short As[64][40];  // inp^T tile [s][c] bf16
  __shared__ __align__(16) unsigned short Bs[64][40];  // W^T tile  [n][c] bf16

  const int tid = threadIdx.x;
  const int w = tid >> 6, lane = tid & 63;
  const int l15 = lane & 15, quad = lane >> 4;

  floatx4 acc[4];
#pragma unroll
  for (int i = 0; i < 4; ++i) acc[i] = (floatx4){0.f, 0.f, 0.f, 0.f};

  for (int cc = 0; cc < 16; ++cc) {
    const int c0 = cc * 32;
    __syncthreads();
#pragma unroll
    for (int t = 0; t < 2; ++t) {  // stage inp^T : 64s x 32c
      const int i = tid * 2 + t;
      const int c = i >> 4, sq = i & 15;
      const floatx4 g = *(const floatx4*)(inp + ((size_t)(b * C_INN + c0 + c) * SEQL + sblk * 64 + sq * 4));
      As[sq * 4 + 0][c] = f2bf(g[0]); As[sq * 4 + 1][c] = f2bf(g[1]);
      As[sq * 4 + 2][c] = f2bf(g[2]); As[sq * 4 + 3][c] = f2bf(g[3]);
    }
#pragma unroll
    for (int t = 0; t < 2; ++t) {  // stage W^T : 64n x 32c
      const int i = tid * 2 + t;
      const int c = i >> 4, nq = i & 15;
      const floatx4 g = *(const floatx4*)(W + ((size_t)(c0 + c) * 1024 + nblk * 64 + nq * 4));
      Bs[nq * 4 + 0][c] = f2bf(g[0]); Bs[nq * 4 + 1][c] = f2bf(g[1]);
      Bs[nq * 4 + 2][c] = f2bf(g[2]); Bs[nq * 4 + 3][c] = f2bf(g[3]);
    }
    __syncthreads();
    const short8 a = *(const short8*)&As[w * 16 + l15][quad * 8];
#pragma unroll
    for (int nt = 0; nt < 4; ++nt) {
      const short8 bb = *(const short8*)&Bs[nt * 16 + l15][quad * 8];
      acc[nt] = __builtin_amdgcn_mfma_f32_16x16x32_bf16(a, bb, acc[nt], 0, 0, 0);
    }
  }

  unsigned short* out = ws + (size_t)p * ((size_t)B_S * N_H * SEQL * D_K);
#pragma unroll
  for (int nt = 0; nt < 4; ++nt) {
    const int h = l15;              // n & 15
    const int d = nblk * 4 + nt;    // n >> 4
#pragma unroll
    for (int r = 0; r < 4; ++r) {
      const int s = sblk * 64 + w * 16 + quad * 4 + r;
      const float vout = acc[nt][r] * sig;
      if (p == 2) out[((size_t)((b * N_H + h) * D_K + d)) * SEQL + s] = f2bf(vout);  // V: [b][v][d][s]
      else        out[((size_t)((b * N_H + h) * SEQL + s)) * D_K + d] = f2bf(vout);  // Q/K: [b][h][s][d]
    }
  }
}

// ---------------------------------------------------------------------------
// Kernel 2: attention with VALU head-mixes. grid(64 qblk, 2 b), 256 thr.
// J = QK^T (MFMA, wave w -> heads 4w..4w+3) -> Jt fp32 LDS -> per-(q,k) thread:
// EL = J.Wl - mask (clamped); pass A accumulates l; pass B builds U=P.Ww ->
// Us bf16 -> O += U.V (MFMA). O written bf16 [b][q][d*16+v].
// ---------------------------------------------------------------------------
__global__ __launch_bounds__(256) void ath_attn(
    const float* __restrict__ maskp,
    const float* __restrict__ Wl,
    const float* __restrict__ Ww,
    const unsigned short* __restrict__ qkv,
    unsigned short* __restrict__ Ob)
{
  const int qblk = blockIdx.x;
  const int b    = blockIdx.y;
  const int tid = threadIdx.x;
  const int w = tid >> 6, lane = tid & 63;
  const int l15 = lane & 15, quad = lane >> 4;
  const int tq = tid >> 4;   // q-local 0..15 (wave w holds tq = 4w..4w+3)
  const int tk = tid & 15;   // k-local 0..15

  const unsigned short* Qf = qkv;
  const unsigned short* Kf = qkv + (size_t)B_S * N_H * SEQL * D_K;
  const unsigned short* Vf = qkv + 2 * (size_t)B_S * N_H * SEQL * D_K;

  __shared__ float Jt[16][16][17];                      // [q][k][h] fp32, padded
  __shared__ float Wls[16][16];                         // Wl[h][g]
  __shared__ float Wws[16][16];                         // Ww[g][v]
  __shared__ float invl_s[16][16];                      // [q][g]
  __shared__ __align__(16) unsigned short Us[16][16][40];  // [v][q][k(32)]

  Wls[tid >> 4][tid & 15] = Wl[tid];
  Wws[tid >> 4][tid & 15] = Ww[tid];

  // Q A-frags for this wave's 4 heads (rows qblk*16 + l15)
  short8 qfr[4][2];
#pragma unroll
  for (int hh = 0; hh < 4; ++hh) {
    const unsigned short* qb = Qf + ((size_t)((b * N_H + (w * 4 + hh)) * SEQL) + qblk * 16 + l15) * D_K;
    qfr[hh][0] = *(const short8*)(qb + quad * 8);
    qfr[hh][1] = *(const short8*)(qb + 32 + quad * 8);
  }

  float l_t[16];
#pragma unroll
  for (int g = 0; g < 16; ++g) l_t[g] = 0.f;

  // ---------------- pass A: l[q][g] over all 1024 k ----------------
  for (int kt = 0; kt < 64; ++kt) {
    const int k0 = kt * 16;
    floatx4 jc[4];
#pragma unroll
    for (int hh = 0; hh < 4; ++hh) {
      const unsigned short* kb = Kf + ((size_t)((b * N_H + (w * 4 + hh)) * SEQL) + k0 + l15) * D_K;
      const short8 kf0 = *(const short8*)(kb + quad * 8);
      const short8 kf1 = *(const short8*)(kb + 32 + quad * 8);
      floatx4 c = (floatx4){0.f, 0.f, 0.f, 0.f};
      c = __builtin_amdgcn_mfma_f32_16x16x32_bf16(qfr[hh][0], kf0, c, 0, 0, 0);
      c = __builtin_amdgcn_mfma_f32_16x16x32_bf16(qfr[hh][1], kf1, c, 0, 0, 0);
      jc[hh] = c;
    }
    __syncthreads();  // prior mix readers done with Jt
#pragma unroll
    for (int hh = 0; hh < 4; ++hh)
#pragma unroll
      for (int r = 0; r < 4; ++r)
        Jt[quad * 4 + r][l15][w * 4 + hh] = jc[hh][r];  // J[q][k][h]
    __syncthreads();
    float Jh[16];
#pragma unroll
    for (int h = 0; h < 16; ++h) Jh[h] = Jt[tq][tk][h];
    const float mk = maskp[b * SEQL + k0 + tk];
#pragma unroll
    for (int g = 0; g < 16; ++g) {
      float e = -mk;
#pragma unroll
      for (int h = 0; h < 16; ++h) e += Jh[h] * Wls[h][g];
      e = fminf(fmaxf(e, -80.f), 80.f);
      l_t[g] += __expf(e);
    }
  }
  // reduce over the 16 tk-threads (contiguous 16-lane groups)
#pragma unroll
  for (int g = 0; g < 16; ++g) {
    float v = l_t[g];
    v += __shfl_xor(v, 1, 16);
    v += __shfl_xor(v, 2, 16);
    v += __shfl_xor(v, 4, 16);
    v += __shfl_xor(v, 8, 16);
    l_t[g] = v;
  }
  if (tk == 0) {
#pragma unroll
    for (int g = 0; g < 16; ++g) invl_s[tq][g] = 1.0f / fmaxf(l_t[g], 1e-37f);
  }
  __syncthreads();

  // ---------------- pass B: O = sum_k (P.Ww) x V ----------------
  floatx4 oacc[4][4];
#pragma unroll
  for (int a = 0; a < 4; ++a)
#pragma unroll
    for (int d = 0; d < 4; ++d) oacc[a][d] = (floatx4){0.f, 0.f, 0.f, 0.f};

  for (int kc = 0; kc < 32; ++kc) {
#pragma unroll 1
    for (int ktl = 0; ktl < 2; ++ktl) {
      const int k0 = kc * 32 + ktl * 16;
      floatx4 jc[4];
#pragma unroll
      for (int hh = 0; hh < 4; ++hh) {
        const unsigned short* kb = Kf + ((size_t)((b * N_H + (w * 4 + hh)) * SEQL) + k0 + l15) * D_K;
        const short8 kf0 = *(const short8*)(kb + quad * 8);
        const short8 kf1 = *(const short8*)(kb + 32 + quad * 8);
        floatx4 c = (floatx4){0.f, 0.f, 0.f, 0.f};
        c = __builtin_amdgcn_mfma_f32_16x16x32_bf16(qfr[hh][0], kf0, c, 0, 0, 0);
        c = __builtin_amdgcn_mfma_f32_16x16x32_bf16(qfr[hh][1], kf1, c, 0, 0, 0);
        jc[hh] = c;
      }
      __syncthreads();  // prior readers of Jt (and V-phase readers of Us) done
#pragma unroll
      for (int hh = 0; hh < 4; ++hh)
#pragma unroll
        for (int r = 0; r < 4; ++r)
          Jt[quad * 4 + r][l15][w * 4 + hh] = jc[hh][r];
      __syncthreads();
      float Jh[16];
#pragma unroll
      for (int h = 0; h < 16; ++h) Jh[h] = Jt[tq][tk][h];
      const float mk = maskp[b * SEQL + k0 + tk];
      float p[16];
#pragma unroll
      for (int g = 0; g < 16; ++g) {
        float e = -mk;
#pragma unroll
        for (int h = 0; h < 16; ++h) e += Jh[h] * Wls[h][g];
        e = fminf(fmaxf(e, -80.f), 80.f);
        p[g] = __expf(e) * invl_s[tq][g];
      }
#pragma unroll
      for (int v = 0; v < 16; ++v) {
        float u = 0.f;
#pragma unroll
        for (int g = 0; g < 16; ++g) u += p[g] * Wws[g][v];
        Us[v][tq][ktl * 16 + tk] = f2bf(u);
      }
    }
    __syncthreads();  // Us complete for this 32-k chunk
    const int kbase = kc * 32;
#pragma unroll
    for (int vv = 0; vv < 4; ++vv) {
      const int v = w * 4 + vv;
      const short8 ufr = *(const short8*)&Us[v][l15][quad * 8];  // A[q=l15][kpos]
#pragma unroll
      for (int dt = 0; dt < 4; ++dt) {
        const unsigned short* vb = Vf + ((size_t)((b * N_H + v) * D_K + dt * 16 + l15)) * SEQL + kbase + quad * 8;
        const short8 vfr = *(const short8*)vb;                    // B[kpos][d]
        oacc[vv][dt] = __builtin_amdgcn_mfma_f32_16x16x32_bf16(ufr, vfr, oacc[vv][dt], 0, 0, 0);
      }
    }
  }

  // write O bf16: Ob[b][q][d*16+v]
#pragma unroll
  for (int vv = 0; vv < 4; ++vv) {
    const int v = w * 4 + vv;
#pragma unroll
    for (int dt = 0; dt < 4; ++dt) {
      const int d = dt * 16 + l15;
#pragma unroll
      for (int r = 0; r < 4; ++r) {
        const int q = qblk * 16 + quad * 4 + r;
        Ob[((size_t)(b * SEQL + q)) * 1024 + d * 16 + v] = f2bf(oacc[vv][dt][r]);
      }
    }
  }
}

// ---------------------------------------------------------------------------
// Kernel 3: out[b][co][q] = inp + sum_j Ob[b][q][j] * Wo[j][co]. fp32 out.
// grid(16 qblk, 8 cblk, 2 b). M=q64, N=co64, K=j1024.
// ---------------------------------------------------------------------------
__global__ __launch_bounds__(256) void ath_out(
    const float* __restrict__ inp,
    const float* __restrict__ Wo,
    const unsigned short* __restrict__ Ob,
    float* __restrict__ out)
{
  const int qblk = blockIdx.x;
  const int cblk = blockIdx.y;
  const int b    = blockIdx.z;
  const int tid = threadIdx.x;
  const int w = tid >> 6, lane = tid & 63;
  const int l15 = lane & 15, quad = lane >> 4;

  __shared__ __align__(16) unsigned short Os[64][40];  // O tile [q][j] bf16
  __shared__ __align__(16) unsigned short Wt[64][40];  // Wo^T tile [co][j] bf16

  floatx4 acc[4];
#pragma unroll
  for (int i = 0; i < 4; ++i) acc[i] = (floatx4){0.f, 0.f, 0.f, 0.f};

  for (int jc = 0; jc < 32; ++jc) {
    const int j0 = jc * 32;
    __syncthreads();
    {  // stage O tile: 64q x 32j, one short8 per thread (Ob already bf16)
      const int q = tid >> 2, jq = tid & 3;
      const unsigned short* g = Ob + ((size_t)(b * SEQL + qblk * 64 + q)) * 1024 + j0 + jq * 8;
      *(short8*)&Os[q][jq * 8] = *(const short8*)g;
    }
#pragma unroll
    for (int t = 0; t < 2; ++t) {  // stage Wo^T: 64co x 32j (fp32 -> bf16)
      const int i = tid * 2 + t;
      const int j = i >> 4, cq = i & 15;
      const floatx4 g = *(const floatx4*)(Wo + ((size_t)(j0 + j) * 512 + cblk * 64 + cq * 4));
      Wt[cq * 4 + 0][j] = f2bf(g[0]); Wt[cq * 4 + 1][j] = f2bf(g[1]);
      Wt[cq * 4 + 2][j] = f2bf(g[2]); Wt[cq * 4 + 3][j] = f2bf(g[3]);
    }
    __syncthreads();
    const short8 a = *(const short8*)&Os[w * 16 + l15][quad * 8];
#pragma unroll
    for (int nt = 0; nt < 4; ++nt) {
      const short8 bb = *(const short8*)&Wt[nt * 16 + l15][quad * 8];
      acc[nt] = __builtin_amdgcn_mfma_f32_16x16x32_bf16(a, bb, acc[nt], 0, 0, 0);
    }
  }

#pragma unroll
  for (int nt = 0; nt < 4; ++nt) {
    const int co = cblk * 64 + nt * 16 + l15;
    const int qb = qblk * 64 + w * 16 + quad * 4;
    const float* ip = inp + ((size_t)(b * 512 + co)) * SEQL + qb;
    float* op = out + ((size_t)(b * 512 + co)) * SEQL + qb;
#pragma unroll
    for (int r = 0; r < 4; ++r) op[r] = acc[nt][r] + ip[r];
  }
}

// ---------------------------------------------------------------------------
extern "C" void kernel_launch(void* const* d_in, const int* in_sizes, int n_in,
                              void* d_out, int out_size, void* d_ws, size_t ws_size,
                              hipStream_t stream) {
  (void)in_sizes; (void)n_in; (void)out_size; (void)ws_size;
  const float* inp   = (const float*)d_in[0];
  const float* maskp = (const float*)d_in[1];
  const float* Wq    = (const float*)d_in[2];
  const float* Wk    = (const float*)d_in[3];
  const float* Wv    = (const float*)d_in[4];
  const float* Aq    = (const float*)d_in[5];
  const float* Ak    = (const float*)d_in[6];
  const float* Av    = (const float*)d_in[7];
  const float* Wl    = (const float*)d_in[8];
  const float* Ww    = (const float*)d_in[9];
  const float* Wo    = (const float*)d_in[10];

  unsigned short* qkv = (unsigned short*)d_ws;  // 3 x 4 MB bf16 (Q, K, V)
  unsigned short* Ob  = (unsigned short*)((char*)d_ws + 3 * (size_t)B_S * N_H * SEQL * D_K * 2);  // 4 MB bf16
  float* out = (float*)d_out;

  ath_qkv<<<dim3(16, 16, 6), 256, 0, stream>>>(inp, Wq, Wk, Wv, Aq, Ak, Av, qkv);
  ath_attn<<<dim3(64, 2), 256, 0, stream>>>(maskp, Wl, Ww, qkv, Ob);
  ath_out<<<dim3(16, 8, 2), 256, 0, stream>>>(inp, Wo, Ob, out);
}

// Round 4
// 466.518 us; speedup vs baseline: 1.4370x; 1.4370x over previous
//
#include <hip/hip_runtime.h>
#include <hip/hip_bf16.h>

// TalkingHeads: BS=2, C_IN=512, SEQ=1024, DK=DV=64, H=16. fp32 I/O, bf16 MFMA compute.
// Round 4: split-k attention (KS chunks of 1024/KS keys per block) to fix the
// 5.95% occupancy / 128-block starvation seen in round 3 (522us ath_attn with
// all pipes idle). Partial l -> reduce -> partial O (bf16) -> sum -> out-proj.

#define B_S  2
#define C_INN 512
#define SEQL 1024
#define D_K  64
#define N_H  16
#define BQJ  (2 * 1024 * 1024)   // elements of one O partial [b][q][j]

typedef __attribute__((ext_vector_type(4))) float floatx4;
typedef __attribute__((ext_vector_type(8))) short short8;

static __device__ __forceinline__ float bf2f(unsigned short u) {
  union { unsigned int i; float f; } x; x.i = ((unsigned int)u) << 16; return x.f;
}
static __device__ __forceinline__ unsigned short f2bf(float f) {
  union { float f; unsigned int i; } x; x.f = f;
  return (unsigned short)((x.i + 0x7fffu + ((x.i >> 16) & 1u)) >> 16);
}

// ---------------------------------------------------------------------------
// Kernel 1: QKV projection (fp32 in, bf16 out).
// Q,K -> [b][h][s][d] bf16 ; V -> [b][v][d][s] bf16.
// ---------------------------------------------------------------------------
__global__ __launch_bounds__(256) void ath_qkv(
    const float* __restrict__ inp,
    const float* __restrict__ Wq,
    const float* __restrict__ Wk,
    const float* __restrict__ Wv,
    const float* __restrict__ Aq,
    const float* __restrict__ Ak,
    const float* __restrict__ Av,
    unsigned short* __restrict__ ws)
{
  const int sblk = blockIdx.x;
  const int nblk = blockIdx.y;
  const int z = blockIdx.z;
  const int b = z / 3, p = z % 3;
  const float* W  = (p == 0) ? Wq : ((p == 1) ? Wk : Wv);
  const float* Ap = (p == 0) ? Aq : ((p == 1) ? Ak : Av);
  const float sig = 1.0f / (1.0f + __expf(-Ap[0]));

  __shared__ __align__(16) unsigned short As[64][40];
  __shared__ __align__(16) unsigned short Bs[64][40];

  const int tid = threadIdx.x;
  const int w = tid >> 6, lane = tid & 63;
  const int l15 = lane & 15, quad = lane >> 4;

  floatx4 acc[4];
#pragma unroll
  for (int i = 0; i < 4; ++i) acc[i] = (floatx4){0.f, 0.f, 0.f, 0.f};

  for (int cc = 0; cc < 16; ++cc) {
    const int c0 = cc * 32;
    __syncthreads();
#pragma unroll
    for (int t = 0; t < 2; ++t) {
      const int i = tid * 2 + t;
      const int c = i >> 4, sq = i & 15;
      const floatx4 g = *(const floatx4*)(inp + ((size_t)(b * C_INN + c0 + c) * SEQL + sblk * 64 + sq * 4));
      As[sq * 4 + 0][c] = f2bf(g[0]); As[sq * 4 + 1][c] = f2bf(g[1]);
      As[sq * 4 + 2][c] = f2bf(g[2]); As[sq * 4 + 3][c] = f2bf(g[3]);
    }
#pragma unroll
    for (int t = 0; t < 2; ++t) {
      const int i = tid * 2 + t;
      const int c = i >> 4, nq = i & 15;
      const floatx4 g = *(const floatx4*)(W + ((size_t)(c0 + c) * 1024 + nblk * 64 + nq * 4));
      Bs[nq * 4 + 0][c] = f2bf(g[0]); Bs[nq * 4 + 1][c] = f2bf(g[1]);
      Bs[nq * 4 + 2][c] = f2bf(g[2]); Bs[nq * 4 + 3][c] = f2bf(g[3]);
    }
    __syncthreads();
    const short8 a = *(const short8*)&As[w * 16 + l15][quad * 8];
#pragma unroll
    for (int nt = 0; nt < 4; ++nt) {
      const short8 bb = *(const short8*)&Bs[nt * 16 + l15][quad * 8];
      acc[nt] = __builtin_amdgcn_mfma_f32_16x16x32_bf16(a, bb, acc[nt], 0, 0, 0);
    }
  }

  unsigned short* out = ws + (size_t)p * ((size_t)B_S * N_H * SEQL * D_K);
#pragma unroll
  for (int nt = 0; nt < 4; ++nt) {
    const int h = l15;
    const int d = nblk * 4 + nt;
#pragma unroll
    for (int r = 0; r < 4; ++r) {
      const int s = sblk * 64 + w * 16 + quad * 4 + r;
      const float vout = acc[nt][r] * sig;
      if (p == 2) out[((size_t)((b * N_H + h) * D_K + d)) * SEQL + s] = f2bf(vout);
      else        out[((size_t)((b * N_H + h) * SEQL + s)) * D_K + d] = f2bf(vout);
    }
  }
}

// ---------------------------------------------------------------------------
// K2a: partial l over k-chunk. grid(64 qblk, KS, 2 b).
// lp[((ks*2+b)*1024+q)*16+g] = sum_{k in chunk} exp(J.Wl - mask)
// ---------------------------------------------------------------------------
__global__ __launch_bounds__(256) void ath_lpart(
    const float* __restrict__ maskp,
    const float* __restrict__ Wl,
    const unsigned short* __restrict__ qkv,
    float* __restrict__ lp,
    int kchunk)
{
  const int qblk = blockIdx.x;
  const int ks   = blockIdx.y;
  const int b    = blockIdx.z;
  const int tid = threadIdx.x;
  const int w = tid >> 6, lane = tid & 63;
  const int l15 = lane & 15, quad = lane >> 4;
  const int tq = tid >> 4, tk = tid & 15;

  const unsigned short* Qf = qkv;
  const unsigned short* Kf = qkv + (size_t)B_S * N_H * SEQL * D_K;

  __shared__ float Jt[16][16][17];
  __shared__ float Wls[16][16];

  Wls[tq][tk] = Wl[tid];

  short8 qfr[4][2];
#pragma unroll
  for (int hh = 0; hh < 4; ++hh) {
    const unsigned short* qb = Qf + ((size_t)((b * N_H + (w * 4 + hh)) * SEQL) + qblk * 16 + l15) * D_K;
    qfr[hh][0] = *(const short8*)(qb + quad * 8);
    qfr[hh][1] = *(const short8*)(qb + 32 + quad * 8);
  }

  float l_t[16];
#pragma unroll
  for (int g = 0; g < 16; ++g) l_t[g] = 0.f;

  const int kt0 = ks * kchunk;
  const int ntile = kchunk >> 4;
#pragma unroll 1
  for (int kt = 0; kt < ntile; ++kt) {
    const int k0 = kt0 + kt * 16;
    floatx4 jc[4];
#pragma unroll
    for (int hh = 0; hh < 4; ++hh) {
      const unsigned short* kb = Kf + ((size_t)((b * N_H + (w * 4 + hh)) * SEQL) + k0 + l15) * D_K;
      const short8 kf0 = *(const short8*)(kb + quad * 8);
      const short8 kf1 = *(const short8*)(kb + 32 + quad * 8);
      floatx4 c = (floatx4){0.f, 0.f, 0.f, 0.f};
      c = __builtin_amdgcn_mfma_f32_16x16x32_bf16(qfr[hh][0], kf0, c, 0, 0, 0);
      c = __builtin_amdgcn_mfma_f32_16x16x32_bf16(qfr[hh][1], kf1, c, 0, 0, 0);
      jc[hh] = c;
    }
    __syncthreads();
#pragma unroll
    for (int hh = 0; hh < 4; ++hh)
#pragma unroll
      for (int r = 0; r < 4; ++r)
        Jt[quad * 4 + r][l15][w * 4 + hh] = jc[hh][r];
    __syncthreads();
    float Jh[16];
#pragma unroll
    for (int h = 0; h < 16; ++h) Jh[h] = Jt[tq][tk][h];
    const float mk = maskp[b * SEQL + k0 + tk];
#pragma unroll
    for (int g = 0; g < 16; ++g) {
      float e = -mk;
#pragma unroll
      for (int h = 0; h < 16; ++h) e += Jh[h] * Wls[h][g];
      e = fminf(fmaxf(e, -80.f), 80.f);
      l_t[g] += __expf(e);
    }
  }
#pragma unroll
  for (int g = 0; g < 16; ++g) {
    float v = l_t[g];
    v += __shfl_xor(v, 1, 16);
    v += __shfl_xor(v, 2, 16);
    v += __shfl_xor(v, 4, 16);
    v += __shfl_xor(v, 8, 16);
    l_t[g] = v;
  }
  if (tk == 0) {
#pragma unroll
    for (int g = 0; g < 16; ++g)
      lp[((size_t)((ks * 2 + b) * SEQL + qblk * 16 + tq)) * 16 + g] = l_t[g];
  }
}

// ---------------------------------------------------------------------------
// K2r: invl[b*16384 + q*16 + g] = 1 / sum_ks lp. grid(128, 256 thr).
// ---------------------------------------------------------------------------
__global__ __launch_bounds__(256) void ath_linv(
    const float* __restrict__ lp, float* __restrict__ invl, int KS)
{
  const int t = blockIdx.x * 256 + threadIdx.x;  // 0..32767
  const int b = t >> 14, rem = t & 16383;
  float s = 0.f;
  for (int ks = 0; ks < KS; ++ks) s += lp[(size_t)((ks * 2 + b)) * 16384 + rem];
  invl[t] = 1.0f / fmaxf(s, 1e-37f);
}

// ---------------------------------------------------------------------------
// K2b: partial O over k-chunk. grid(64 qblk, KS, 2 b).
// Obp[ks*BQJ + (b*1024+q)*1024 + d*16+v] bf16.
// ---------------------------------------------------------------------------
__global__ __launch_bounds__(256) void ath_opart(
    const float* __restrict__ maskp,
    const float* __restrict__ Wl,
    const float* __restrict__ Ww,
    const unsigned short* __restrict__ qkv,
    const float* __restrict__ invl,
    unsigned short* __restrict__ Obp,
    int kchunk)
{
  const int qblk = blockIdx.x;
  const int ks   = blockIdx.y;
  const int b    = blockIdx.z;
  const int tid = threadIdx.x;
  const int w = tid >> 6, lane = tid & 63;
  const int l15 = lane & 15, quad = lane >> 4;
  const int tq = tid >> 4, tk = tid & 15;

  const unsigned short* Qf = qkv;
  const unsigned short* Kf = qkv + (size_t)B_S * N_H * SEQL * D_K;
  const unsigned short* Vf = qkv + 2 * (size_t)B_S * N_H * SEQL * D_K;

  __shared__ float Jt[16][16][17];
  __shared__ float Wls[16][16];
  __shared__ float Wws[16][16];
  __shared__ float invl_s[16][16];
  __shared__ __align__(16) unsigned short Us[16][16][40];

  Wls[tq][tk] = Wl[tid];
  Wws[tq][tk] = Ww[tid];
  invl_s[tq][tk] = invl[(size_t)b * 16384 + (qblk * 16 + tq) * 16 + tk];

  short8 qfr[4][2];
#pragma unroll
  for (int hh = 0; hh < 4; ++hh) {
    const unsigned short* qb = Qf + ((size_t)((b * N_H + (w * 4 + hh)) * SEQL) + qblk * 16 + l15) * D_K;
    qfr[hh][0] = *(const short8*)(qb + quad * 8);
    qfr[hh][1] = *(const short8*)(qb + 32 + quad * 8);
  }

  floatx4 oacc[4][4];
#pragma unroll
  for (int a = 0; a < 4; ++a)
#pragma unroll
    for (int d = 0; d < 4; ++d) oacc[a][d] = (floatx4){0.f, 0.f, 0.f, 0.f};

  __syncthreads();  // invl_s/Wls/Wws visible

  const int nchunk = kchunk >> 5;
  const int kbase0 = ks * kchunk;
#pragma unroll 1
  for (int kc = 0; kc < nchunk; ++kc) {
#pragma unroll 1
    for (int ktl = 0; ktl < 2; ++ktl) {
      const int k0 = kbase0 + kc * 32 + ktl * 16;
      floatx4 jc[4];
#pragma unroll
      for (int hh = 0; hh < 4; ++hh) {
        const unsigned short* kb = Kf + ((size_t)((b * N_H + (w * 4 + hh)) * SEQL) + k0 + l15) * D_K;
        const short8 kf0 = *(const short8*)(kb + quad * 8);
        const short8 kf1 = *(const short8*)(kb + 32 + quad * 8);
        floatx4 c = (floatx4){0.f, 0.f, 0.f, 0.f};
        c = __builtin_amdgcn_mfma_f32_16x16x32_bf16(qfr[hh][0], kf0, c, 0, 0, 0);
        c = __builtin_amdgcn_mfma_f32_16x16x32_bf16(qfr[hh][1], kf1, c, 0, 0, 0);
        jc[hh] = c;
      }
      __syncthreads();  // prior Jt readers + prior V-phase Us readers done
#pragma unroll
      for (int hh = 0; hh < 4; ++hh)
#pragma unroll
        for (int r = 0; r < 4; ++r)
          Jt[quad * 4 + r][l15][w * 4 + hh] = jc[hh][r];
      __syncthreads();
      float Jh[16];
#pragma unroll
      for (int h = 0; h < 16; ++h) Jh[h] = Jt[tq][tk][h];
      const float mk = maskp[b * SEQL + k0 + tk];
      float p[16];
#pragma unroll
      for (int g = 0; g < 16; ++g) {
        float e = -mk;
#pragma unroll
        for (int h = 0; h < 16; ++h) e += Jh[h] * Wls[h][g];
        e = fminf(fmaxf(e, -80.f), 80.f);
        p[g] = __expf(e) * invl_s[tq][g];
      }
#pragma unroll
      for (int v = 0; v < 16; ++v) {
        float u = 0.f;
#pragma unroll
        for (int g = 0; g < 16; ++g) u += p[g] * Wws[g][v];
        Us[v][tq][ktl * 16 + tk] = f2bf(u);
      }
    }
    __syncthreads();
    const int kbase = kbase0 + kc * 32;
#pragma unroll
    for (int vv = 0; vv < 4; ++vv) {
      const int v = w * 4 + vv;
      const short8 ufr = *(const short8*)&Us[v][l15][quad * 8];
#pragma unroll
      for (int dt = 0; dt < 4; ++dt) {
        const unsigned short* vb = Vf + ((size_t)((b * N_H + v) * D_K + dt * 16 + l15)) * SEQL + kbase + quad * 8;
        const short8 vfr = *(const short8*)vb;
        oacc[vv][dt] = __builtin_amdgcn_mfma_f32_16x16x32_bf16(ufr, vfr, oacc[vv][dt], 0, 0, 0);
      }
    }
  }

#pragma unroll
  for (int vv = 0; vv < 4; ++vv) {
    const int v = w * 4 + vv;
#pragma unroll
    for (int dt = 0; dt < 4; ++dt) {
      const int d = dt * 16 + l15;
#pragma unroll
      for (int r = 0; r < 4; ++r) {
        const int q = qblk * 16 + quad * 4 + r;
        Obp[(size_t)ks * BQJ + ((size_t)(b * SEQL + q)) * 1024 + d * 16 + v] = f2bf(oacc[vv][dt][r]);
      }
    }
  }
}

// ---------------------------------------------------------------------------
// K2s: Obsum = sum_ks Obp. grid(1024, 256 thr), short8 per thread.
// ---------------------------------------------------------------------------
__global__ __launch_bounds__(256) void ath_osum(
    const unsigned short* __restrict__ Obp,
    unsigned short* __restrict__ Obsum, int KS)
{
  const size_t i = ((size_t)blockIdx.x * 256 + threadIdx.x) * 8;
  float a[8];
#pragma unroll
  for (int e = 0; e < 8; ++e) a[e] = 0.f;
  for (int ks = 0; ks < KS; ++ks) {
    const short8 v = *(const short8*)(Obp + (size_t)ks * BQJ + i);
#pragma unroll
    for (int e = 0; e < 8; ++e) a[e] += bf2f((unsigned short)v[e]);
  }
  short8 o;
#pragma unroll
  for (int e = 0; e < 8; ++e) o[e] = (short)f2bf(a[e]);
  *(short8*)(Obsum + i) = o;
}

// ---------------------------------------------------------------------------
// Fallback fused attention (round-3, correct at 16 MB ws). grid(64, 2).
// ---------------------------------------------------------------------------
__global__ __launch_bounds__(256) void ath_attn(
    const float* __restrict__ maskp,
    const float* __restrict__ Wl,
    const float* __restrict__ Ww,
    const unsigned short* __restrict__ qkv,
    unsigned short* __restrict__ Ob)
{
  const int qblk = blockIdx.x;
  const int b    = blockIdx.y;
  const int tid = threadIdx.x;
  const int w = tid >> 6, lane = tid & 63;
  const int l15 = lane & 15, quad = lane >> 4;
  const int tq = tid >> 4, tk = tid & 15;

  const unsigned short* Qf = qkv;
  const unsigned short* Kf = qkv + (size_t)B_S * N_H * SEQL * D_K;
  const unsigned short* Vf = qkv + 2 * (size_t)B_S * N_H * SEQL * D_K;

  __shared__ float Jt[16][16][17];
  __shared__ float Wls[16][16];
  __shared__ float Wws[16][16];
  __shared__ float invl_s[16][16];
  __shared__ __align__(16) unsigned short Us[16][16][40];

  Wls[tq][tk] = Wl[tid];
  Wws[tq][tk] = Ww[tid];

  short8 qfr[4][2];
#pragma unroll
  for (int hh = 0; hh < 4; ++hh) {
    const unsigned short* qb = Qf + ((size_t)((b * N_H + (w * 4 + hh)) * SEQL) + qblk * 16 + l15) * D_K;
    qfr[hh][0] = *(const short8*)(qb + quad * 8);
    qfr[hh][1] = *(const short8*)(qb + 32 + quad * 8);
  }

  float l_t[16];
#pragma unroll
  for (int g = 0; g < 16; ++g) l_t[g] = 0.f;

  for (int kt = 0; kt < 64; ++kt) {
    const int k0 = kt * 16;
    floatx4 jc[4];
#pragma unroll
    for (int hh = 0; hh < 4; ++hh) {
      const unsigned short* kb = Kf + ((size_t)((b * N_H + (w * 4 + hh)) * SEQL) + k0 + l15) * D_K;
      const short8 kf0 = *(const short8*)(kb + quad * 8);
      const short8 kf1 = *(const short8*)(kb + 32 + quad * 8);
      floatx4 c = (floatx4){0.f, 0.f, 0.f, 0.f};
      c = __builtin_amdgcn_mfma_f32_16x16x32_bf16(qfr[hh][0], kf0, c, 0, 0, 0);
      c = __builtin_amdgcn_mfma_f32_16x16x32_bf16(qfr[hh][1], kf1, c, 0, 0, 0);
      jc[hh] = c;
    }
    __syncthreads();
#pragma unroll
    for (int hh = 0; hh < 4; ++hh)
#pragma unroll
      for (int r = 0; r < 4; ++r)
        Jt[quad * 4 + r][l15][w * 4 + hh] = jc[hh][r];
    __syncthreads();
    float Jh[16];
#pragma unroll
    for (int h = 0; h < 16; ++h) Jh[h] = Jt[tq][tk][h];
    const float mk = maskp[b * SEQL + k0 + tk];
#pragma unroll
    for (int g = 0; g < 16; ++g) {
      float e = -mk;
#pragma unroll
      for (int h = 0; h < 16; ++h) e += Jh[h] * Wls[h][g];
      e = fminf(fmaxf(e, -80.f), 80.f);
      l_t[g] += __expf(e);
    }
  }
#pragma unroll
  for (int g = 0; g < 16; ++g) {
    float v = l_t[g];
    v += __shfl_xor(v, 1, 16);
    v += __shfl_xor(v, 2, 16);
    v += __shfl_xor(v, 4, 16);
    v += __shfl_xor(v, 8, 16);
    l_t[g] = v;
  }
  if (tk == 0) {
#pragma unroll
    for (int g = 0; g < 16; ++g) invl_s[tq][g] = 1.0f / fmaxf(l_t[g], 1e-37f);
  }
  __syncthreads();

  floatx4 oacc[4][4];
#pragma unroll
  for (int a = 0; a < 4; ++a)
#pragma unroll
    for (int d = 0; d < 4; ++d) oacc[a][d] = (floatx4){0.f, 0.f, 0.f, 0.f};

  for (int kc = 0; kc < 32; ++kc) {
#pragma unroll 1
    for (int ktl = 0; ktl < 2; ++ktl) {
      const int k0 = kc * 32 + ktl * 16;
      floatx4 jc[4];
#pragma unroll
      for (int hh = 0; hh < 4; ++hh) {
        const unsigned short* kb = Kf + ((size_t)((b * N_H + (w * 4 + hh)) * SEQL) + k0 + l15) * D_K;
        const short8 kf0 = *(const short8*)(kb + quad * 8);
        const short8 kf1 = *(const short8*)(kb + 32 + quad * 8);
        floatx4 c = (floatx4){0.f, 0.f, 0.f, 0.f};
        c = __builtin_amdgcn_mfma_f32_16x16x32_bf16(qfr[hh][0], kf0, c, 0, 0, 0);
        c = __builtin_amdgcn_mfma_f32_16x16x32_bf16(qfr[hh][1], kf1, c, 0, 0, 0);
        jc[hh] = c;
      }
      __syncthreads();
#pragma unroll
      for (int hh = 0; hh < 4; ++hh)
#pragma unroll
        for (int r = 0; r < 4; ++r)
          Jt[quad * 4 + r][l15][w * 4 + hh] = jc[hh][r];
      __syncthreads();
      float Jh[16];
#pragma unroll
      for (int h = 0; h < 16; ++h) Jh[h] = Jt[tq][tk][h];
      const float mk = maskp[b * SEQL + k0 + tk];
      float p[16];
#pragma unroll
      for (int g = 0; g < 16; ++g) {
        float e = -mk;
#pragma unroll
        for (int h = 0; h < 16; ++h) e += Jh[h] * Wls[h][g];
        e = fminf(fmaxf(e, -80.f), 80.f);
        p[g] = __expf(e) * invl_s[tq][g];
      }
#pragma unroll
      for (int v = 0; v < 16; ++v) {
        float u = 0.f;
#pragma unroll
        for (int g = 0; g < 16; ++g) u += p[g] * Wws[g][v];
        Us[v][tq][ktl * 16 + tk] = f2bf(u);
      }
    }
    __syncthreads();
    const int kbase = kc * 32;
#pragma unroll
    for (int vv = 0; vv < 4; ++vv) {
      const int v = w * 4 + vv;
      const short8 ufr = *(const short8*)&Us[v][l15][quad * 8];
#pragma unroll
      for (int dt = 0; dt < 4; ++dt) {
        const unsigned short* vb = Vf + ((size_t)((b * N_H + v) * D_K + dt * 16 + l15)) * SEQL + kbase + quad * 8;
        const short8 vfr = *(const short8*)vb;
        oacc[vv][dt] = __builtin_amdgcn_mfma_f32_16x16x32_bf16(ufr, vfr, oacc[vv][dt], 0, 0, 0);
      }
    }
  }

#pragma unroll
  for (int vv = 0; vv < 4; ++vv) {
    const int v = w * 4 + vv;
#pragma unroll
    for (int dt = 0; dt < 4; ++dt) {
      const int d = dt * 16 + l15;
#pragma unroll
      for (int r = 0; r < 4; ++r) {
        const int q = qblk * 16 + quad * 4 + r;
        Ob[((size_t)(b * SEQL + q)) * 1024 + d * 16 + v] = f2bf(oacc[vv][dt][r]);
      }
    }
  }
}

// ---------------------------------------------------------------------------
// Kernel 3: out[b][co][q] = inp + sum_j Ob[b][q][j] * Wo[j][co]. fp32 out.
// ---------------------------------------------------------------------------
__global__ __launch_bounds__(256) void ath_out(
    const float* __restrict__ inp,
    const float* __restrict__ Wo,
    const unsigned short* __restrict__ Ob,
    float* __restrict__ out)
{
  const int qblk = blockIdx.x;
  const int cblk = blockIdx.y;
  const int b    = blockIdx.z;
  const int tid = threadIdx.x;
  const int w = tid >> 6, lane = tid & 63;
  const int l15 = lane & 15, quad = lane >> 4;

  __shared__ __align__(16) unsigned short Os[64][40];
  __shared__ __align__(16) unsigned short Wt[64][40];

  floatx4 acc[4];
#pragma unroll
  for (int i = 0; i < 4; ++i) acc[i] = (floatx4){0.f, 0.f, 0.f, 0.f};

  for (int jc = 0; jc < 32; ++jc) {
    const int j0 = jc * 32;
    __syncthreads();
    {
      const int q = tid >> 2, jq = tid & 3;
      const unsigned short* g = Ob + ((size_t)(b * SEQL + qblk * 64 + q)) * 1024 + j0 + jq * 8;
      *(short8*)&Os[q][jq * 8] = *(const short8*)g;
    }
#pragma unroll
    for (int t = 0; t < 2; ++t) {
      const int i = tid * 2 + t;
      const int j = i >> 4, cq = i & 15;
      const floatx4 g = *(const floatx4*)(Wo + ((size_t)(j0 + j) * 512 + cblk * 64 + cq * 4));
      Wt[cq * 4 + 0][j] = f2bf(g[0]); Wt[cq * 4 + 1][j] = f2bf(g[1]);
      Wt[cq * 4 + 2][j] = f2bf(g[2]); Wt[cq * 4 + 3][j] = f2bf(g[3]);
    }
    __syncthreads();
    const short8 a = *(const short8*)&Os[w * 16 + l15][quad * 8];
#pragma unroll
    for (int nt = 0; nt < 4; ++nt) {
      const short8 bb = *(const short8*)&Wt[nt * 16 + l15][quad * 8];
      acc[nt] = __builtin_amdgcn_mfma_f32_16x16x32_bf16(a, bb, acc[nt], 0, 0, 0);
    }
  }

#pragma unroll
  for (int nt = 0; nt < 4; ++nt) {
    const int co = cblk * 64 + nt * 16 + l15;
    const int qb = qblk * 64 + w * 16 + quad * 4;
    const float* ip = inp + ((size_t)(b * 512 + co)) * SEQL + qb;
    float* op = out + ((size_t)(b * 512 + co)) * SEQL + qb;
#pragma unroll
    for (int r = 0; r < 4; ++r) op[r] = acc[nt][r] + ip[r];
  }
}

// ---------------------------------------------------------------------------
extern "C" void kernel_launch(void* const* d_in, const int* in_sizes, int n_in,
                              void* d_out, int out_size, void* d_ws, size_t ws_size,
                              hipStream_t stream) {
  (void)in_sizes; (void)n_in; (void)out_size;
  const float* inp   = (const float*)d_in[0];
  const float* maskp = (const float*)d_in[1];
  const float* Wq    = (const float*)d_in[2];
  const float* Wk    = (const float*)d_in[3];
  const float* Wv    = (const float*)d_in[4];
  const float* Aq    = (const float*)d_in[5];
  const float* Ak    = (const float*)d_in[6];
  const float* Av    = (const float*)d_in[7];
  const float* Wl    = (const float*)d_in[8];
  const float* Ww    = (const float*)d_in[9];
  const float* Wo    = (const float*)d_in[10];

  const size_t MB = 1u << 20;
  unsigned short* qkv   = (unsigned short*)d_ws;                       // 12 MB bf16 Q,K,V
  unsigned short* Obsum = (unsigned short*)((char*)d_ws + 12 * MB);    // 4 MB bf16
  float*          lp    = (float*)((char*)d_ws + 16 * MB);             // <=1 MB
  float*          invl  = (float*)((char*)d_ws + 17 * MB);             // 128 KB
  unsigned short* Obp   = (unsigned short*)((char*)d_ws + 18 * MB);    // KS*4 MB
  float* out = (float*)d_out;

  const int KS = (ws_size >= 50 * MB) ? 8 : (ws_size >= 34 * MB) ? 4
               : (ws_size >= 26 * MB) ? 2 : 0;

  ath_qkv<<<dim3(16, 16, 6), 256, 0, stream>>>(inp, Wq, Wk, Wv, Aq, Ak, Av, qkv);
  if (KS > 0) {
    const int kchunk = SEQL / KS;
    ath_lpart<<<dim3(64, KS, 2), 256, 0, stream>>>(maskp, Wl, qkv, lp, kchunk);
    ath_linv<<<dim3(128), 256, 0, stream>>>(lp, invl, KS);
    ath_opart<<<dim3(64, KS, 2), 256, 0, stream>>>(maskp, Wl, Ww, qkv, invl, Obp, kchunk);
    ath_osum<<<dim3(1024), 256, 0, stream>>>(Obp, Obsum, KS);
  } else {
    ath_attn<<<dim3(64, 2), 256, 0, stream>>>(maskp, Wl, Ww, qkv, Obsum);
  }
  ath_out<<<dim3(16, 8, 2), 256, 0, stream>>>(inp, Wo, Obsum, out);
}

// Round 6
// 361.269 us; speedup vs baseline: 1.8557x; 1.2913x over previous
//
#include <hip/hip_runtime.h>
#include <hip/hip_bf16.h>

// TalkingHeads: BS=2, C_IN=512, SEQ=1024, DK=DV=64, H=16. fp32 I/O.
// Round 6: round-5 structure with compile fixes. Mixes use packed _Float16x2
// vector math (v_pk_fma_f16) with Wl/Ww columns in registers; J stored as f16
// pairs in wave-private LDS (no barriers in J->EL->U; P overwrites J in-place,
// wave-lockstep-safe). PV uses the round-4-proven mfma_f32_16x16x32_bf16 with
// bf16 V and a 64-k Us buffer (stride 68 shorts -> conflict-free).

#define B_S  2
#define C_INN 512
#define SEQL 1024
#define D_K  64
#define N_H  16
#define BQJ  (2 * 1024 * 1024)   // elements of one O partial [b][q][j]
#define KSL  16                  // lpart split
#define KSO  8                   // opart split

typedef __attribute__((ext_vector_type(4))) float floatx4;
typedef __attribute__((ext_vector_type(8))) short short8;
typedef __fp16 h2raw __attribute__((ext_vector_type(2)));   // cvt_pkrtz return type
typedef _Float16 h2 __attribute__((ext_vector_type(2)));    // arithmetic type

static __device__ __forceinline__ float bf2f(unsigned short u) {
  union { unsigned int i; float f; } x; x.i = ((unsigned int)u) << 16; return x.f;
}
static __device__ __forceinline__ unsigned short f2bf(float f) {
  union { float f; unsigned int i; } x; x.f = f;
  return (unsigned short)((x.i + 0x7fffu + ((x.i >> 16) & 1u)) >> 16);
}
static __device__ __forceinline__ unsigned int pkh2(float a, float b) {
  h2raw r = __builtin_amdgcn_cvt_pkrtz(a, b);
  union { h2raw h; unsigned int u; } x; x.h = r; return x.u;
}
static __device__ __forceinline__ h2 u2h(unsigned int u) {
  union { unsigned int u; h2 h; } x; x.u = u; return x.h;
}
static __device__ __forceinline__ unsigned int pkbf(float a, float b) {
  return (unsigned int)f2bf(a) | ((unsigned int)f2bf(b) << 16);
}

// ---------------------------------------------------------------------------
// Kernel 1: QKV projection (fp32 in, bf16 out).
// Q,K -> [b][h][s][d] ; V -> [b][v][d][s].
// ---------------------------------------------------------------------------
__global__ __launch_bounds__(256) void ath_qkv(
    const float* __restrict__ inp,
    const float* __restrict__ Wq,
    const float* __restrict__ Wk,
    const float* __restrict__ Wv,
    const float* __restrict__ Aq,
    const float* __restrict__ Ak,
    const float* __restrict__ Av,
    unsigned short* __restrict__ ws)
{
  const int sblk = blockIdx.x;
  const int nblk = blockIdx.y;
  const int z = blockIdx.z;
  const int b = z / 3, p = z % 3;
  const float* W  = (p == 0) ? Wq : ((p == 1) ? Wk : Wv);
  const float* Ap = (p == 0) ? Aq : ((p == 1) ? Ak : Av);
  const float sig = 1.0f / (1.0f + __expf(-Ap[0]));

  __shared__ __align__(16) unsigned short As[64][40];
  __shared__ __align__(16) unsigned short Bs[64][40];

  const int tid = threadIdx.x;
  const int w = tid >> 6, lane = tid & 63;
  const int l15 = lane & 15, quad = lane >> 4;

  floatx4 acc[4];
#pragma unroll
  for (int i = 0; i < 4; ++i) acc[i] = (floatx4){0.f, 0.f, 0.f, 0.f};

  for (int cc = 0; cc < 16; ++cc) {
    const int c0 = cc * 32;
    __syncthreads();
#pragma unroll
    for (int t = 0; t < 2; ++t) {
      const int i = tid * 2 + t;
      const int c = i >> 4, sq = i & 15;
      const floatx4 g = *(const floatx4*)(inp + ((size_t)(b * C_INN + c0 + c) * SEQL + sblk * 64 + sq * 4));
      As[sq * 4 + 0][c] = f2bf(g[0]); As[sq * 4 + 1][c] = f2bf(g[1]);
      As[sq * 4 + 2][c] = f2bf(g[2]); As[sq * 4 + 3][c] = f2bf(g[3]);
    }
#pragma unroll
    for (int t = 0; t < 2; ++t) {
      const int i = tid * 2 + t;
      const int c = i >> 4, nq = i & 15;
      const floatx4 g = *(const floatx4*)(W + ((size_t)(c0 + c) * 1024 + nblk * 64 + nq * 4));
      Bs[nq * 4 + 0][c] = f2bf(g[0]); Bs[nq * 4 + 1][c] = f2bf(g[1]);
      Bs[nq * 4 + 2][c] = f2bf(g[2]); Bs[nq * 4 + 3][c] = f2bf(g[3]);
    }
    __syncthreads();
    const short8 a = *(const short8*)&As[w * 16 + l15][quad * 8];
#pragma unroll
    for (int nt = 0; nt < 4; ++nt) {
      const short8 bb = *(const short8*)&Bs[nt * 16 + l15][quad * 8];
      acc[nt] = __builtin_amdgcn_mfma_f32_16x16x32_bf16(a, bb, acc[nt], 0, 0, 0);
    }
  }

  unsigned short* out = ws + (size_t)p * ((size_t)B_S * N_H * SEQL * D_K);
#pragma unroll
  for (int nt = 0; nt < 4; ++nt) {
    const int h = l15;
    const int d = nblk * 4 + nt;
#pragma unroll
    for (int r = 0; r < 4; ++r) {
      const int s = sblk * 64 + w * 16 + quad * 4 + r;
      const float vout = acc[nt][r] * sig;
      if (p == 2) out[((size_t)((b * N_H + h) * D_K + d)) * SEQL + s] = f2bf(vout);
      else        out[((size_t)((b * N_H + h) * SEQL + s)) * D_K + d] = f2bf(vout);
    }
  }
}

// ---------------------------------------------------------------------------
// K2a: partial l. grid(64 qblk, KSL, 2 b). Wave w owns k-tile w (16 k), all 16
// heads. Barrier-free J->EL chain inside the wave.
// ---------------------------------------------------------------------------
__global__ __launch_bounds__(256, 4) void ath_lpart(
    const float* __restrict__ maskp,
    const float* __restrict__ Wl,
    const unsigned short* __restrict__ qkv,
    float* __restrict__ lp)
{
  const int qblk = blockIdx.x;
  const int ks   = blockIdx.y;
  const int b    = blockIdx.z;
  const int tid = threadIdx.x;
  const int w = tid >> 6, lane = tid & 63;
  const int l15 = lane & 15, quad = lane >> 4;

  const unsigned short* Qf = qkv;
  const unsigned short* Kf = qkv + (size_t)B_S * N_H * SEQL * D_K;

  __shared__ unsigned int JtU[4][2304];  // [k16][q16][hp8+pad1] f16 pairs, 36 KB
  __shared__ float Ms[SEQL];             // 4 KB

  {
    const floatx4 mv = *(const floatx4*)(maskp + b * SEQL + tid * 4);
    *(floatx4*)&Ms[tid * 4] = mv;
  }

  // Wl columns (g = quad*4+gg) as f16 pairs over h
  unsigned int WlTp[4][8];
#pragma unroll
  for (int gg = 0; gg < 4; ++gg)
#pragma unroll
    for (int hp = 0; hp < 8; ++hp)
      WlTp[gg][hp] = pkh2(Wl[(2 * hp) * 16 + quad * 4 + gg],
                          Wl[(2 * hp + 1) * 16 + quad * 4 + gg]);

  __syncthreads();  // Ms visible

  const int kabs0 = ks * (SEQL / KSL) + w * 16;

  // ---- J for all 16 heads of this wave's tile ----
#pragma unroll
  for (int hg = 0; hg < 2; ++hg) {
    floatx4 jc[8];
#pragma unroll
    for (int hh = 0; hh < 8; ++hh) {
      const int h = hg * 8 + hh;
      const unsigned short* qb = Qf + ((size_t)((b * N_H + h) * SEQL) + qblk * 16 + l15) * D_K;
      const unsigned short* kb = Kf + ((size_t)((b * N_H + h) * SEQL) + kabs0 + l15) * D_K;
      const short8 q0 = *(const short8*)(qb + quad * 8);
      const short8 q1 = *(const short8*)(qb + 32 + quad * 8);
      const short8 k0 = *(const short8*)(kb + quad * 8);
      const short8 k1 = *(const short8*)(kb + 32 + quad * 8);
      floatx4 c = (floatx4){0.f, 0.f, 0.f, 0.f};
      c = __builtin_amdgcn_mfma_f32_16x16x32_bf16(q0, k0, c, 0, 0, 0);
      c = __builtin_amdgcn_mfma_f32_16x16x32_bf16(q1, k1, c, 0, 0, 0);
      jc[hh] = c;
    }
#pragma unroll
    for (int r = 0; r < 4; ++r) {
      const int base = (l15 * 16 + quad * 4 + r) * 9 + hg * 4;
#pragma unroll
      for (int jj = 0; jj < 4; ++jj)
        JtU[w][base + jj] = pkh2(jc[2 * jj][r], jc[2 * jj + 1][r]);
    }
  }

  // ---- EL mix + exp + l accumulate. Lane role: q=l15, g=quad*4+gg ----
  float l_acc[4] = {0.f, 0.f, 0.f, 0.f};
#pragma unroll 4
  for (int k = 0; k < 16; ++k) {
    const int jb = (k * 16 + l15) * 9;
    unsigned int ju[8];
#pragma unroll
    for (int hp = 0; hp < 8; ++hp) ju[hp] = JtU[w][jb + hp];
    const float m = Ms[kabs0 + k];
    h2 eh[4] = {(h2)(_Float16)0, (h2)(_Float16)0, (h2)(_Float16)0, (h2)(_Float16)0};
#pragma unroll
    for (int hp = 0; hp < 8; ++hp) {
      const h2 jv = u2h(ju[hp]);
      eh[0] += jv * u2h(WlTp[0][hp]);
      eh[1] += jv * u2h(WlTp[1][hp]);
      eh[2] += jv * u2h(WlTp[2][hp]);
      eh[3] += jv * u2h(WlTp[3][hp]);
    }
#pragma unroll
    for (int gg = 0; gg < 4; ++gg) {
      const float e = (float)eh[gg][0] + (float)eh[gg][1] - m;
      l_acc[gg] += __expf(fminf(fmaxf(e, -60.f), 60.f));
    }
  }

  // ---- cross-wave reduce over the 4 k-tiles (reuse JtU slice 0) ----
  __syncthreads();
  float* Ls = (float*)&JtU[0][0];
#pragma unroll
  for (int gg = 0; gg < 4; ++gg)
    Ls[w * 256 + l15 * 16 + quad * 4 + gg] = l_acc[gg];
  __syncthreads();
  {
    const float s = Ls[tid] + Ls[256 + tid] + Ls[512 + tid] + Ls[768 + tid];
    const int q = tid >> 4, g = tid & 15;
    lp[((size_t)((ks * 2 + b) * SEQL + qblk * 16 + q)) * 16 + g] = s;
  }
}

// ---------------------------------------------------------------------------
// K2r: invl = 1 / sum_ks lp. grid(128, 256 thr).
// ---------------------------------------------------------------------------
__global__ __launch_bounds__(256) void ath_linv(
    const float* __restrict__ lp, float* __restrict__ invl)
{
  const int t = blockIdx.x * 256 + threadIdx.x;
  const int b = t >> 14, rem = t & 16383;
  float s = 0.f;
#pragma unroll
  for (int ks = 0; ks < KSL; ++ks) s += lp[(size_t)((ks * 2 + b)) * 16384 + rem];
  invl[t] = 1.0f / fmaxf(s, 1e-37f);
}

// ---------------------------------------------------------------------------
// K2b: partial O. grid(64 qblk, KSO, 2 b). kchunk=128 -> 2 rounds of 64 k.
// Per round: wave w owns k-tile rd*4+w (J->EL->U barrier-free), barrier,
// cross-wave V-phase (mfma 16x16x32 bf16, wave w: v=4w..4w+3), barrier.
// ---------------------------------------------------------------------------
__global__ __launch_bounds__(256, 2) void ath_opart(
    const float* __restrict__ maskp,
    const float* __restrict__ Wl,
    const float* __restrict__ Ww,
    const unsigned short* __restrict__ qkv,
    const float* __restrict__ invl,
    unsigned short* __restrict__ Obp)
{
  const int qblk = blockIdx.x;
  const int ks   = blockIdx.y;
  const int b    = blockIdx.z;
  const int tid = threadIdx.x;
  const int w = tid >> 6, lane = tid & 63;
  const int l15 = lane & 15, quad = lane >> 4;

  const unsigned short* Qf = qkv;
  const unsigned short* Kf = qkv + (size_t)B_S * N_H * SEQL * D_K;
  const unsigned short* Vf = qkv + 2 * (size_t)B_S * N_H * SEQL * D_K;

  __shared__ unsigned int JtU[4][2304];   // per-wave J/P slice, 36 KB
  __shared__ unsigned int UsU[16 * 16 * 34];  // U bf16 [v16][q16][k64 pad->34 uints], 34.8 KB
  __shared__ float Ms[SEQL];              // 4 KB

  {
    const floatx4 mv = *(const floatx4*)(maskp + b * SEQL + tid * 4);
    *(floatx4*)&Ms[tid * 4] = mv;
  }

  unsigned int WlTp[4][8], WwTp[4][8];
#pragma unroll
  for (int gg = 0; gg < 4; ++gg)
#pragma unroll
    for (int hp = 0; hp < 8; ++hp) {
      WlTp[gg][hp] = pkh2(Wl[(2 * hp) * 16 + quad * 4 + gg],
                          Wl[(2 * hp + 1) * 16 + quad * 4 + gg]);
      WwTp[gg][hp] = pkh2(Ww[(2 * hp) * 16 + quad * 4 + gg],
                          Ww[(2 * hp + 1) * 16 + quad * 4 + gg]);
    }

  float inv[4];
#pragma unroll
  for (int gg = 0; gg < 4; ++gg)
    inv[gg] = invl[(size_t)b * 16384 + (qblk * 16 + l15) * 16 + quad * 4 + gg];

  floatx4 oacc[4][4];
#pragma unroll
  for (int a = 0; a < 4; ++a)
#pragma unroll
    for (int d = 0; d < 4; ++d) oacc[a][d] = (floatx4){0.f, 0.f, 0.f, 0.f};

  __syncthreads();  // Ms visible

  const int kchunk = SEQL / KSO;   // 128

  for (int rd = 0; rd < 2; ++rd) {
    const int kabs0 = ks * kchunk + (rd * 4 + w) * 16;

    // ---- J for all 16 heads (wave-private) ----
#pragma unroll
    for (int hg = 0; hg < 2; ++hg) {
      floatx4 jc[8];
#pragma unroll
      for (int hh = 0; hh < 8; ++hh) {
        const int h = hg * 8 + hh;
        const unsigned short* qb = Qf + ((size_t)((b * N_H + h) * SEQL) + qblk * 16 + l15) * D_K;
        const unsigned short* kb = Kf + ((size_t)((b * N_H + h) * SEQL) + kabs0 + l15) * D_K;
        const short8 q0 = *(const short8*)(qb + quad * 8);
        const short8 q1 = *(const short8*)(qb + 32 + quad * 8);
        const short8 k0 = *(const short8*)(kb + quad * 8);
        const short8 k1 = *(const short8*)(kb + 32 + quad * 8);
        floatx4 c = (floatx4){0.f, 0.f, 0.f, 0.f};
        c = __builtin_amdgcn_mfma_f32_16x16x32_bf16(q0, k0, c, 0, 0, 0);
        c = __builtin_amdgcn_mfma_f32_16x16x32_bf16(q1, k1, c, 0, 0, 0);
        jc[hh] = c;
      }
#pragma unroll
      for (int r = 0; r < 4; ++r) {
        const int base = (l15 * 16 + quad * 4 + r) * 9 + hg * 4;
#pragma unroll
        for (int jj = 0; jj < 4; ++jj)
          JtU[w][base + jj] = pkh2(jc[2 * jj][r], jc[2 * jj + 1][r]);
      }
    }

    // ---- EL mix -> P f16 pairs, in-place over J (wave-lockstep-safe) ----
#pragma unroll 4
    for (int k = 0; k < 16; ++k) {
      const int jb = (k * 16 + l15) * 9;
      unsigned int ju[8];
#pragma unroll
      for (int hp = 0; hp < 8; ++hp) ju[hp] = JtU[w][jb + hp];
      const float m = Ms[kabs0 + k];
      h2 eh[4] = {(h2)(_Float16)0, (h2)(_Float16)0, (h2)(_Float16)0, (h2)(_Float16)0};
#pragma unroll
      for (int hp = 0; hp < 8; ++hp) {
        const h2 jv = u2h(ju[hp]);
        eh[0] += jv * u2h(WlTp[0][hp]);
        eh[1] += jv * u2h(WlTp[1][hp]);
        eh[2] += jv * u2h(WlTp[2][hp]);
        eh[3] += jv * u2h(WlTp[3][hp]);
      }
      float p[4];
#pragma unroll
      for (int gg = 0; gg < 4; ++gg) {
        const float e = (float)eh[gg][0] + (float)eh[gg][1] - m;
        p[gg] = __expf(fminf(fmaxf(e, -60.f), 60.f)) * inv[gg];
      }
      JtU[w][jb + quad * 2 + 0] = pkh2(p[0], p[1]);
      JtU[w][jb + quad * 2 + 1] = pkh2(p[2], p[3]);
    }

    // ---- U mix: lane role q=l15, v=quad*4+vv -> Us bf16 [v][q][klocal] ----
#pragma unroll 4
    for (int kp = 0; kp < 8; ++kp) {
      float ue[4] = {0.f, 0.f, 0.f, 0.f}, uo[4] = {0.f, 0.f, 0.f, 0.f};
#pragma unroll
      for (int par = 0; par < 2; ++par) {
        const int jb = ((kp * 2 + par) * 16 + l15) * 9;
        unsigned int pu[8];
#pragma unroll
        for (int gp = 0; gp < 8; ++gp) pu[gp] = JtU[w][jb + gp];
        h2 uh[4] = {(h2)(_Float16)0, (h2)(_Float16)0, (h2)(_Float16)0, (h2)(_Float16)0};
#pragma unroll
        for (int gp = 0; gp < 8; ++gp) {
          const h2 pv = u2h(pu[gp]);
          uh[0] += pv * u2h(WwTp[0][gp]);
          uh[1] += pv * u2h(WwTp[1][gp]);
          uh[2] += pv * u2h(WwTp[2][gp]);
          uh[3] += pv * u2h(WwTp[3][gp]);
        }
        float* u = par ? uo : ue;
#pragma unroll
        for (int vv = 0; vv < 4; ++vv) u[vv] = (float)uh[vv][0] + (float)uh[vv][1];
      }
#pragma unroll
      for (int vv = 0; vv < 4; ++vv)
        UsU[((quad * 4 + vv) * 16 + l15) * 34 + w * 8 + kp] = pkbf(ue[vv], uo[vv]);
    }

    __syncthreads();  // all waves' Us slices ready

    // ---- V-phase: wave w -> v = 4w..4w+3; K=32 bf16 MFMA over 2 k-pairs ----
    const unsigned short* UsS = (const unsigned short*)UsU;
#pragma unroll
    for (int tp = 0; tp < 2; ++tp) {
      const int kt_abs = ks * kchunk + rd * 64 + tp * 32;
#pragma unroll
      for (int vv = 0; vv < 4; ++vv) {
        const int v = w * 4 + vv;
        const short8 ufr = *(const short8*)&UsS[((v * 16 + l15) * 34) * 2 + tp * 32 + quad * 8];
#pragma unroll
        for (int dt = 0; dt < 4; ++dt) {
          const short8 vfr = *(const short8*)(Vf +
              ((size_t)((b * N_H + v) * D_K + dt * 16 + l15)) * SEQL + kt_abs + quad * 8);
          oacc[vv][dt] = __builtin_amdgcn_mfma_f32_16x16x32_bf16(ufr, vfr, oacc[vv][dt], 0, 0, 0);
        }
      }
    }

    __syncthreads();  // Us free for next round
  }

  // write partial O bf16: Obp[ks][b][q][d*16+v]
#pragma unroll
  for (int vv = 0; vv < 4; ++vv) {
    const int v = w * 4 + vv;
#pragma unroll
    for (int dt = 0; dt < 4; ++dt) {
      const int d = dt * 16 + l15;
#pragma unroll
      for (int r = 0; r < 4; ++r) {
        const int q = qblk * 16 + quad * 4 + r;
        Obp[(size_t)ks * BQJ + ((size_t)(b * SEQL + q)) * 1024 + d * 16 + v] = f2bf(oacc[vv][dt][r]);
      }
    }
  }
}

// ---------------------------------------------------------------------------
// K2s: Obsum = sum_ks Obp. grid(1024, 256 thr).
// ---------------------------------------------------------------------------
__global__ __launch_bounds__(256) void ath_osum(
    const unsigned short* __restrict__ Obp,
    unsigned short* __restrict__ Obsum)
{
  const size_t i = ((size_t)blockIdx.x * 256 + threadIdx.x) * 8;
  float a[8];
#pragma unroll
  for (int e = 0; e < 8; ++e) a[e] = 0.f;
#pragma unroll
  for (int ks = 0; ks < KSO; ++ks) {
    const short8 v = *(const short8*)(Obp + (size_t)ks * BQJ + i);
#pragma unroll
    for (int e = 0; e < 8; ++e) a[e] += bf2f((unsigned short)v[e]);
  }
  short8 o;
#pragma unroll
  for (int e = 0; e < 8; ++e) o[e] = (short)f2bf(a[e]);
  *(short8*)(Obsum + i) = o;
}

// ---------------------------------------------------------------------------
// Kernel 3: out[b][co][q] = inp + sum_j Obsum[b][q][j] * Wo[j][co]. fp32 out.
// ---------------------------------------------------------------------------
__global__ __launch_bounds__(256) void ath_out(
    const float* __restrict__ inp,
    const float* __restrict__ Wo,
    const unsigned short* __restrict__ Ob,
    float* __restrict__ out)
{
  const int qblk = blockIdx.x;
  const int cblk = blockIdx.y;
  const int b    = blockIdx.z;
  const int tid = threadIdx.x;
  const int w = tid >> 6, lane = tid & 63;
  const int l15 = lane & 15, quad = lane >> 4;

  __shared__ __align__(16) unsigned short Os[64][40];
  __shared__ __align__(16) unsigned short Wt[64][40];

  floatx4 acc[4];
#pragma unroll
  for (int i = 0; i < 4; ++i) acc[i] = (floatx4){0.f, 0.f, 0.f, 0.f};

  for (int jc = 0; jc < 32; ++jc) {
    const int j0 = jc * 32;
    __syncthreads();
    {
      const int q = tid >> 2, jq = tid & 3;
      const unsigned short* g = Ob + ((size_t)(b * SEQL + qblk * 64 + q)) * 1024 + j0 + jq * 8;
      *(short8*)&Os[q][jq * 8] = *(const short8*)g;
    }
#pragma unroll
    for (int t = 0; t < 2; ++t) {
      const int i = tid * 2 + t;
      const int j = i >> 4, cq = i & 15;
      const floatx4 g = *(const floatx4*)(Wo + ((size_t)(j0 + j) * 512 + cblk * 64 + cq * 4));
      Wt[cq * 4 + 0][j] = f2bf(g[0]); Wt[cq * 4 + 1][j] = f2bf(g[1]);
      Wt[cq * 4 + 2][j] = f2bf(g[2]); Wt[cq * 4 + 3][j] = f2bf(g[3]);
    }
    __syncthreads();
    const short8 a = *(const short8*)&Os[w * 16 + l15][quad * 8];
#pragma unroll
    for (int nt = 0; nt < 4; ++nt) {
      const short8 bb = *(const short8*)&Wt[nt * 16 + l15][quad * 8];
      acc[nt] = __builtin_amdgcn_mfma_f32_16x16x32_bf16(a, bb, acc[nt], 0, 0, 0);
    }
  }

#pragma unroll
  for (int nt = 0; nt < 4; ++nt) {
    const int co = cblk * 64 + nt * 16 + l15;
    const int qb = qblk * 64 + w * 16 + quad * 4;
    const float* ip = inp + ((size_t)(b * 512 + co)) * SEQL + qb;
    float* op = out + ((size_t)(b * 512 + co)) * SEQL + qb;
#pragma unroll
    for (int r = 0; r < 4; ++r) op[r] = acc[nt][r] + ip[r];
  }
}

// ---------------------------------------------------------------------------
extern "C" void kernel_launch(void* const* d_in, const int* in_sizes, int n_in,
                              void* d_out, int out_size, void* d_ws, size_t ws_size,
                              hipStream_t stream) {
  (void)in_sizes; (void)n_in; (void)out_size; (void)ws_size;
  const float* inp   = (const float*)d_in[0];
  const float* maskp = (const float*)d_in[1];
  const float* Wq    = (const float*)d_in[2];
  const float* Wk    = (const float*)d_in[3];
  const float* Wv    = (const float*)d_in[4];
  const float* Aq    = (const float*)d_in[5];
  const float* Ak    = (const float*)d_in[6];
  const float* Av    = (const float*)d_in[7];
  const float* Wl    = (const float*)d_in[8];
  const float* Ww    = (const float*)d_in[9];
  const float* Wo    = (const float*)d_in[10];

  const size_t MB = 1u << 20;
  unsigned short* qkv   = (unsigned short*)d_ws;                       // 12 MB bf16 Q,K,V
  unsigned short* Obsum = (unsigned short*)((char*)d_ws + 12 * MB);    // 4 MB bf16
  float*          invl  = (float*)((char*)d_ws + 16 * MB);             // 128 KB
  float*          lp    = (float*)((char*)d_ws + 18 * MB);             // 2 MB (dead before Obp use)
  unsigned short* Obp   = (unsigned short*)((char*)d_ws + 18 * MB);    // KSO*4 MB = 32 MB
  float* out = (float*)d_out;

  ath_qkv<<<dim3(16, 16, 6), 256, 0, stream>>>(inp, Wq, Wk, Wv, Aq, Ak, Av, qkv);
  ath_lpart<<<dim3(64, KSL, 2), 256, 0, stream>>>(maskp, Wl, qkv, lp);
  ath_linv<<<dim3(128), 256, 0, stream>>>(lp, invl);
  ath_opart<<<dim3(64, KSO, 2), 256, 0, stream>>>(maskp, Wl, Ww, qkv, invl, Obp);
  ath_osum<<<dim3(1024), 256, 0, stream>>>(Obp, Obsum);
  ath_out<<<dim3(16, 8, 2), 256, 0, stream>>>(inp, Wo, Obsum, out);
}